// Round 1
// baseline (268.646 us; speedup 1.0000x reference)
//
#include <hip/hip_runtime.h>
#include <hip/hip_bf16.h>

// GCN layer: out[b,n,o] = dis[b,n] * sum_m adj[b,n,m] * dis[b,m] * (x[b,m,:]@W[o,:] + bias[o])
//
// R8: K3 = 2-phase double-buffered pipeline (T3 minimum template). R7 serialized
// [stage -> drain -> compute]; HBM idle during compute (duty ~70%). Now: two
// 24KB buffer halves (BK=64), issue next tile's global_load_lds BEFORE consuming
// current, one vmcnt(0)+barrier per tile (32 barriers total, same as R7's 16x2).
// Loads get the whole compute phase to fly; each block issues HBM back-to-back.
// K2: register prefetch of kk+1's float4s under the MFMA phase (was fully
// latency-exposed at 1 block/CU).

#define BATCH 8
#define NN    2048
#define DIN   256
#define DOUT  256
#define RTOT  (BATCH * NN)   // 16384
#define AP    (NN + 32)      // 2080  padded abf row stride (elems)
#define HP    (RTOT + 32)    // 16416 padded hT row stride (elems)

typedef short  bf16x8  __attribute__((ext_vector_type(8)));
typedef short  short4v __attribute__((ext_vector_type(4)));
typedef float  f32x4   __attribute__((ext_vector_type(4)));

__device__ __forceinline__ short f2bf(float f) {
    union { float f; unsigned u; } v; v.f = f;
    unsigned r = v.u + 0x7fffu + ((v.u >> 16) & 1u);   // RNE
    return (short)(r >> 16);
}

__device__ __forceinline__ void gl_lds16(const unsigned short* g, unsigned short* l) {
    __builtin_amdgcn_global_load_lds(
        (const __attribute__((address_space(1))) unsigned int*)g,
        (__attribute__((address_space(3))) unsigned int*)l, 16, 0, 0);
}

// ---------------- K1: degrees -> dis, and adj -> bf16 (padded rows) ----------------
__global__ __launch_bounds__(256) void k_degree_cvt(const float* __restrict__ adj,
                                                    float* __restrict__ dis,
                                                    unsigned short* __restrict__ abf) {
    const int row = blockIdx.x;                 // 0..16383
    const int n = row & (NN - 1);
    const int tid = threadIdx.x;
    const float4* rp4 = (const float4*)(adj + (size_t)row * NN);
    unsigned short* op = abf + (size_t)row * AP;

    float s = 0.f;
#pragma unroll
    for (int i = 0; i < 2; i++) {
        float4 v = rp4[tid + i * 256];
        s += (v.x + v.y) + (v.z + v.w);
        short4v sv = { f2bf(v.x), f2bf(v.y), f2bf(v.z), f2bf(v.w) };
        *(short4v*)(op + 4 * (tid + i * 256)) = sv;
    }
#pragma unroll
    for (int off = 32; off; off >>= 1) s += __shfl_down(s, off);
    __shared__ float red[4];
    if ((tid & 63) == 0) red[tid >> 6] = s;
    __syncthreads();
    if (tid == 0) {
        float tot  = (red[0] + red[1]) + (red[2] + red[3]);
        float diag = ((const float*)rp4)[n];
        dis[row]   = rsqrtf(tot - diag);
    }
}

// ---------------- K2: projection, transposed + dis-folded, padded hT ----------------
__global__ __launch_bounds__(256) void k_proj(const float* __restrict__ x,
                                              const float* __restrict__ W,
                                              const float* __restrict__ bias,
                                              const float* __restrict__ dis,
                                              unsigned short* __restrict__ hT) {
    const int mt  = blockIdx.y;           // 0..1   (o-tile of 128)
    const int nt  = blockIdx.x;           // 0..127 (r-tile of 128)
    const int tid = threadIdx.x;
    const int w = tid >> 6, lane = tid & 63;
    const int wr = w >> 1, wc = w & 1;
    const int l16 = lane & 15, quad = lane >> 4;

    __shared__ short As[128][32];
    __shared__ short Bs[128][32];

    f32x4 acc[4][4];
#pragma unroll
    for (int i = 0; i < 4; i++)
#pragma unroll
        for (int j = 0; j < 4; j++) acc[i][j] = (f32x4){0.f, 0.f, 0.f, 0.f};

    const float4* Wf4 = (const float4*)(W + (size_t)mt * 128 * DIN);
    const float4* Xf4 = (const float4*)(x + (size_t)nt * 128 * DIN);

    const int idx_r = tid >> 3;            // row within 128, for it-strided loads
    const int idx_c = tid & 7;             // float4 column within 8

    // prologue: preload kk=0
    float4 va[4], vb[4];
#pragma unroll
    for (int it = 0; it < 4; it++) {
        int idx = tid + it * 256;
        int r = idx >> 3, c = idx & 7;
        va[it] = Wf4[(size_t)r * (DIN / 4) + c];
        vb[it] = Xf4[(size_t)r * (DIN / 4) + c];
    }
    (void)idx_r; (void)idx_c;

    for (int kk = 0; kk < DIN / 32; kk++) {
        __syncthreads();                   // previous iter's ds_reads retired
#pragma unroll
        for (int it = 0; it < 4; it++) {
            int idx = tid + it * 256;
            int r = idx >> 3, c = idx & 7;
            short4v sa = { f2bf(va[it].x), f2bf(va[it].y), f2bf(va[it].z), f2bf(va[it].w) };
            short4v sb = { f2bf(vb[it].x), f2bf(vb[it].y), f2bf(vb[it].z), f2bf(vb[it].w) };
            *(short4v*)&As[r][c * 4] = sa;
            *(short4v*)&Bs[r][c * 4] = sb;
        }
        __syncthreads();
        // prefetch kk+1: loads fly under the MFMA phase below
        if (kk < DIN / 32 - 1) {
#pragma unroll
            for (int it = 0; it < 4; it++) {
                int idx = tid + it * 256;
                int r = idx >> 3, c = idx & 7;
                va[it] = Wf4[(size_t)r * (DIN / 4) + (kk + 1) * 8 + c];
                vb[it] = Xf4[(size_t)r * (DIN / 4) + (kk + 1) * 8 + c];
            }
        }
        bf16x8 af[4], bfv[4];
#pragma unroll
        for (int i = 0; i < 4; i++) af[i]  = *(bf16x8*)&As[wr * 64 + i * 16 + l16][quad * 8];
#pragma unroll
        for (int j = 0; j < 4; j++) bfv[j] = *(bf16x8*)&Bs[wc * 64 + j * 16 + l16][quad * 8];
#pragma unroll
        for (int i = 0; i < 4; i++)
#pragma unroll
            for (int j = 0; j < 4; j++)
                acc[i][j] = __builtin_amdgcn_mfma_f32_16x16x32_bf16(af[i], bfv[j], acc[i][j], 0, 0, 0);
    }

#pragma unroll
    for (int i = 0; i < 4; i++) {
        const int orow_base = mt * 128 + wr * 64 + i * 16 + quad * 4;
#pragma unroll
        for (int r = 0; r < 4; r++) {
            const int orow = orow_base + r;
            const float bb = bias[orow];
#pragma unroll
            for (int j = 0; j < 4; j++) {
                const int col = nt * 128 + wc * 64 + j * 16 + l16;
                float v = (acc[i][j][r] + bb) * dis[col];
                hT[(size_t)orow * HP + col] = (unsigned short)f2bf(v);
            }
        }
    }
}

// ---------------- K3: out = dis[n] * (abf @ hT), BK=64 x 2-buffer pipeline ----------------
// Per batch: M=2048(n), K=2048(m), N=256(o). Block tile 64x128. Grid 512 = 2 blocks/CU:
// bx&7=batch (XCD L2 affinity for hT), (bx>>3)&31=mtile, bx>>8=ctile; co-resident
// ctile pair shares adj rows (L2 dedup). Per tile t: issue next tile's 6 gl_lds16
// per thread, then consume current (16 MFMA + 12 ds_read per wave), then ONE
// vmcnt(0)+barrier. Loads overlap the compute phase -> HBM issue back-to-back.
__global__ __launch_bounds__(256, 2) void k_main(const unsigned short* __restrict__ abf,
                                                 const unsigned short* __restrict__ hT,
                                                 const float* __restrict__ dis,
                                                 float* __restrict__ out) {
    const int bx    = blockIdx.x;
    const int b     = bx & 7;
    const int mtile = (bx >> 3) & 31;
    const int ctile = bx >> 8;            // 0..1
    const int n0    = mtile * 64;
    const int tid  = threadIdx.x;
    const int w    = tid >> 6, lane = tid & 63;
    const int l16  = lane & 15, quad = lane >> 4;
    const int lr   = lane >> 2;           // 0..15 (staging row-within-group)
    const int lc   = (lane & 3) * 8;      // 0,8,16,24 (staging elem offset)

    __shared__ short As[2][2][64][32];    // 16 KB: [buf][sub] adj rows(n) x 32k
    __shared__ short Bs[2][2][128][32];   // 32 KB: [buf][sub] hT rows(o) x 32k

    const unsigned short* agp  = abf + (size_t)(b * NN + n0 + w * 16 + lr) * AP + lc;
    const unsigned short* bgp0 = hT + (size_t)(ctile * 128 + w * 32 + lr) * HP + b * NN + lc;
    const unsigned short* bgp1 = bgp0 + (size_t)16 * HP;

    f32x4 acc[4][2];
#pragma unroll
    for (int i = 0; i < 4; i++)
#pragma unroll
        for (int j = 0; j < 2; j++) acc[i][j] = (f32x4){0.f, 0.f, 0.f, 0.f};

    // prologue: stage tile 0 into buf 0
#pragma unroll
    for (int s = 0; s < 2; s++) {
        gl_lds16(agp + s * 32,  (unsigned short*)&As[0][s][w * 16][0]);
        gl_lds16(bgp0 + s * 32, (unsigned short*)&Bs[0][s][w * 32][0]);
        gl_lds16(bgp1 + s * 32, (unsigned short*)&Bs[0][s][w * 32 + 16][0]);
    }
    __syncthreads();

    for (int t = 0; t < NN / 64; t++) {           // 32 tiles
        const int cur = t & 1;
        // issue next tile's staging FIRST — flies under this tile's compute
        if (t < NN / 64 - 1) {
            const int ko = (t + 1) * 64;
#pragma unroll
            for (int s = 0; s < 2; s++) {
                gl_lds16(agp + ko + s * 32,  (unsigned short*)&As[cur ^ 1][s][w * 16][0]);
                gl_lds16(bgp0 + ko + s * 32, (unsigned short*)&Bs[cur ^ 1][s][w * 32][0]);
                gl_lds16(bgp1 + ko + s * 32, (unsigned short*)&Bs[cur ^ 1][s][w * 32 + 16][0]);
            }
        }
        // consume current buffer: 16 MFMA + 12 ds_read_b128 per wave
#pragma unroll
        for (int s = 0; s < 2; s++) {
            bf16x8 af[4], bfv[2];
#pragma unroll
            for (int i = 0; i < 4; i++) af[i]  = *(bf16x8*)&As[cur][s][i * 16 + l16][quad * 8];
#pragma unroll
            for (int j = 0; j < 2; j++) bfv[j] = *(bf16x8*)&Bs[cur][s][w * 32 + j * 16 + l16][quad * 8];
#pragma unroll
            for (int i = 0; i < 4; i++)
#pragma unroll
                for (int j = 0; j < 2; j++)
                    acc[i][j] = __builtin_amdgcn_mfma_f32_16x16x32_bf16(af[i], bfv[j], acc[i][j], 0, 0, 0);
        }
        __syncthreads();   // drains next-tile loads (had full compute phase to fly)
    }

    const float* disb = dis + (size_t)b * NN;
#pragma unroll
    for (int i = 0; i < 4; i++) {
#pragma unroll
        for (int r = 0; r < 4; r++) {
            const int nrow = n0 + i * 16 + quad * 4 + r;
            const float dn = disb[nrow];
#pragma unroll
            for (int j = 0; j < 2; j++) {
                const int ocol = ctile * 128 + w * 32 + j * 16 + l16;
                out[((size_t)b * NN + nrow) * DOUT + ocol] = dn * acc[i][j][r];
            }
        }
    }
}

extern "C" void kernel_launch(void* const* d_in, const int* in_sizes, int n_in,
                              void* d_out, int out_size, void* d_ws, size_t ws_size,
                              hipStream_t stream) {
    const float* x    = (const float*)d_in[0];
    const float* adj  = (const float*)d_in[1];
    const float* W    = (const float*)d_in[2];
    const float* bias = (const float*)d_in[3];
    float* out = (float*)d_out;

    float* dis = (float*)d_ws;                                             // 64 KB
    unsigned short* hT  = (unsigned short*)((char*)d_ws + 65536);          // 256*16416*2 = 8.4 MB
    unsigned short* abf = (unsigned short*)((char*)d_ws + 65536 + (size_t)DOUT * HP * 2); // 68 MB

    k_degree_cvt<<<RTOT, 256, 0, stream>>>(adj, dis, abf);
    k_proj<<<dim3(128, 2), 256, 0, stream>>>(x, W, bias, dis, hT);
    k_main<<<512, 256, 0, stream>>>(abf, hT, dis, out);
}

// Round 2
// 260.086 us; speedup vs baseline: 1.0329x; 1.0329x over previous
//
#include <hip/hip_runtime.h>
#include <hip/hip_bf16.h>

// GCN layer: out[b,n,o] = dis[b,n] * sum_m adj[b,n,m] * dis[b,m] * (x[b,m,:]@W[o,:] + bias[o])
//
// R9: K3 = counted-vmcnt double-buffer pipeline (T3+T4, m218/m201 mechanism).
// R8's lesson: __syncthreads() emits s_waitcnt vmcnt(0) BEFORE the barrier ->
// prefetch never overlapped, and 32 drains instead of 16 regressed +8.7us.
// Now: BK=64 x 2 buffers, stage 2 tiles ahead; per tile:
//   s_waitcnt vmcnt(6)  (tile t's 6 loads done, t+1's 6 stay IN FLIGHT)
//   raw s_barrier -> compute -> lgkmcnt(0) -> raw s_barrier -> stage(t+2)
// Raw barriers carry no implicit vmcnt(0), so HBM issue never drains to zero
// in the steady state. K1/K2 are R7-verbatim (single-variable change).

#define BATCH 8
#define NN    2048
#define DIN   256
#define DOUT  256
#define RTOT  (BATCH * NN)   // 16384
#define AP    (NN + 32)      // 2080  padded abf row stride (elems)
#define HP    (RTOT + 32)    // 16416 padded hT row stride (elems)

typedef short  bf16x8  __attribute__((ext_vector_type(8)));
typedef short  short4v __attribute__((ext_vector_type(4)));
typedef float  f32x4   __attribute__((ext_vector_type(4)));

__device__ __forceinline__ short f2bf(float f) {
    union { float f; unsigned u; } v; v.f = f;
    unsigned r = v.u + 0x7fffu + ((v.u >> 16) & 1u);   // RNE
    return (short)(r >> 16);
}

__device__ __forceinline__ void gl_lds16(const unsigned short* g, unsigned short* l) {
    __builtin_amdgcn_global_load_lds(
        (const __attribute__((address_space(1))) unsigned int*)g,
        (__attribute__((address_space(3))) unsigned int*)l, 16, 0, 0);
}

// ---------------- K1: degrees -> dis, and adj -> bf16 (padded rows) ----------------
__global__ __launch_bounds__(256) void k_degree_cvt(const float* __restrict__ adj,
                                                    float* __restrict__ dis,
                                                    unsigned short* __restrict__ abf) {
    const int row = blockIdx.x;                 // 0..16383
    const int n = row & (NN - 1);
    const int tid = threadIdx.x;
    const float4* rp4 = (const float4*)(adj + (size_t)row * NN);
    unsigned short* op = abf + (size_t)row * AP;

    float s = 0.f;
#pragma unroll
    for (int i = 0; i < 2; i++) {
        float4 v = rp4[tid + i * 256];
        s += (v.x + v.y) + (v.z + v.w);
        short4v sv = { f2bf(v.x), f2bf(v.y), f2bf(v.z), f2bf(v.w) };
        *(short4v*)(op + 4 * (tid + i * 256)) = sv;
    }
#pragma unroll
    for (int off = 32; off; off >>= 1) s += __shfl_down(s, off);
    __shared__ float red[4];
    if ((tid & 63) == 0) red[tid >> 6] = s;
    __syncthreads();
    if (tid == 0) {
        float tot  = (red[0] + red[1]) + (red[2] + red[3]);
        float diag = ((const float*)rp4)[n];
        dis[row]   = rsqrtf(tot - diag);
    }
}

// ---------------- K2: projection, transposed + dis-folded, padded hT ----------------
__global__ __launch_bounds__(256) void k_proj(const float* __restrict__ x,
                                              const float* __restrict__ W,
                                              const float* __restrict__ bias,
                                              const float* __restrict__ dis,
                                              unsigned short* __restrict__ hT) {
    const int mt  = blockIdx.y;           // 0..1   (o-tile of 128)
    const int nt  = blockIdx.x;           // 0..127 (r-tile of 128)
    const int tid = threadIdx.x;
    const int w = tid >> 6, lane = tid & 63;
    const int wr = w >> 1, wc = w & 1;
    const int l16 = lane & 15, quad = lane >> 4;

    __shared__ short As[128][32];
    __shared__ short Bs[128][32];

    f32x4 acc[4][4];
#pragma unroll
    for (int i = 0; i < 4; i++)
#pragma unroll
        for (int j = 0; j < 4; j++) acc[i][j] = (f32x4){0.f, 0.f, 0.f, 0.f};

    const float4* Wf4 = (const float4*)(W + (size_t)mt * 128 * DIN);
    const float4* Xf4 = (const float4*)(x + (size_t)nt * 128 * DIN);

    for (int kk = 0; kk < DIN / 32; kk++) {
        const int k0 = kk * 32;
        __syncthreads();
#pragma unroll
        for (int it = 0; it < 4; it++) {
            int idx = tid + it * 256;
            int r = idx >> 3, c = idx & 7;
            float4 va = Wf4[(size_t)r * (DIN / 4) + (k0 >> 2) + c];
            float4 vb = Xf4[(size_t)r * (DIN / 4) + (k0 >> 2) + c];
            short4v sa = { f2bf(va.x), f2bf(va.y), f2bf(va.z), f2bf(va.w) };
            short4v sb = { f2bf(vb.x), f2bf(vb.y), f2bf(vb.z), f2bf(vb.w) };
            *(short4v*)&As[r][c * 4] = sa;
            *(short4v*)&Bs[r][c * 4] = sb;
        }
        __syncthreads();
        bf16x8 af[4], bfv[4];
#pragma unroll
        for (int i = 0; i < 4; i++) af[i]  = *(bf16x8*)&As[wr * 64 + i * 16 + l16][quad * 8];
#pragma unroll
        for (int j = 0; j < 4; j++) bfv[j] = *(bf16x8*)&Bs[wc * 64 + j * 16 + l16][quad * 8];
#pragma unroll
        for (int i = 0; i < 4; i++)
#pragma unroll
            for (int j = 0; j < 4; j++)
                acc[i][j] = __builtin_amdgcn_mfma_f32_16x16x32_bf16(af[i], bfv[j], acc[i][j], 0, 0, 0);
    }

#pragma unroll
    for (int i = 0; i < 4; i++) {
        const int orow_base = mt * 128 + wr * 64 + i * 16 + quad * 4;
#pragma unroll
        for (int r = 0; r < 4; r++) {
            const int orow = orow_base + r;
            const float bb = bias[orow];
#pragma unroll
            for (int j = 0; j < 4; j++) {
                const int col = nt * 128 + wc * 64 + j * 16 + l16;
                float v = (acc[i][j][r] + bb) * dis[col];
                hT[(size_t)orow * HP + col] = (unsigned short)f2bf(v);
            }
        }
    }
}

// ---------------- K3: out = dis[n] * (abf @ hT), BK=64 dbuf + counted vmcnt ----------------
// Per batch: M=2048(n), K=2048(m), N=256(o). Block tile 64x128. Grid 512 = 2 blocks/CU:
// bx&7=batch (XCD L2 affinity for hT), (bx>>3)&31=mtile, bx>>8=ctile.
// Pipeline depth 2: stage(t+2) issued after compute(t); vmcnt(6) at top of each
// tile leaves next tile's 6 loads in flight across both raw barriers.
__global__ __launch_bounds__(256, 2) void k_main(const unsigned short* __restrict__ abf,
                                                 const unsigned short* __restrict__ hT,
                                                 const float* __restrict__ dis,
                                                 float* __restrict__ out) {
    const int bx    = blockIdx.x;
    const int b     = bx & 7;
    const int mtile = (bx >> 3) & 31;
    const int ctile = bx >> 8;            // 0..1
    const int n0    = mtile * 64;
    const int tid  = threadIdx.x;
    const int w    = tid >> 6, lane = tid & 63;
    const int l16  = lane & 15, quad = lane >> 4;
    const int lr   = lane >> 2;           // 0..15 (staging row-within-group)
    const int lc   = (lane & 3) * 8;      // 0,8,16,24 (staging elem offset)

    __shared__ short As[2][2][64][32];    // 16 KB: [buf][sub] adj rows(n) x 32k
    __shared__ short Bs[2][2][128][32];   // 32 KB: [buf][sub] hT rows(o) x 32k

    const unsigned short* agp  = abf + (size_t)(b * NN + n0 + w * 16 + lr) * AP + lc;
    const unsigned short* bgp0 = hT + (size_t)(ctile * 128 + w * 32 + lr) * HP + b * NN + lc;
    const unsigned short* bgp1 = bgp0 + (size_t)16 * HP;

    f32x4 acc[4][2];
#pragma unroll
    for (int i = 0; i < 4; i++)
#pragma unroll
        for (int j = 0; j < 2; j++) acc[i][j] = (f32x4){0.f, 0.f, 0.f, 0.f};

#define STAGE(T, BUF)                                                              \
    do {                                                                           \
        const int ko_ = (T) * 64;                                                  \
        _Pragma("unroll")                                                          \
        for (int s_ = 0; s_ < 2; s_++) {                                           \
            gl_lds16(agp  + ko_ + s_ * 32, (unsigned short*)&As[BUF][s_][w * 16][0]);      \
            gl_lds16(bgp0 + ko_ + s_ * 32, (unsigned short*)&Bs[BUF][s_][w * 32][0]);      \
            gl_lds16(bgp1 + ko_ + s_ * 32, (unsigned short*)&Bs[BUF][s_][w * 32 + 16][0]); \
        }                                                                          \
    } while (0)

#define COMPUTE(BUF)                                                               \
    do {                                                                           \
        _Pragma("unroll")                                                          \
        for (int s = 0; s < 2; s++) {                                              \
            bf16x8 af[4], bfv[2];                                                  \
            _Pragma("unroll")                                                      \
            for (int i = 0; i < 4; i++) af[i]  = *(bf16x8*)&As[BUF][s][i * 16 + l16][quad * 8];        \
            _Pragma("unroll")                                                      \
            for (int j = 0; j < 2; j++) bfv[j] = *(bf16x8*)&Bs[BUF][s][w * 32 + j * 16 + l16][quad * 8]; \
            _Pragma("unroll")                                                      \
            for (int i = 0; i < 4; i++)                                            \
                _Pragma("unroll")                                                  \
                for (int j = 0; j < 2; j++)                                        \
                    acc[i][j] = __builtin_amdgcn_mfma_f32_16x16x32_bf16(af[i], bfv[j], acc[i][j], 0, 0, 0); \
        }                                                                          \
    } while (0)

    // prologue: stage tiles 0 and 1 -> 12 loads/wave outstanding
    STAGE(0, 0);
    STAGE(1, 1);

    for (int t = 0; t < NN / 64 - 1; t++) {       // t = 0..30
        const int cur = t & 1;
        // tile t's 6 loads done; tile (t+1)'s 6 remain in flight across barriers
        asm volatile("s_waitcnt vmcnt(6)" ::: "memory");
        __builtin_amdgcn_s_barrier();
        COMPUTE(cur);
        // all this wave's ds_reads retired -> buffer safe to overwrite after barrier
        asm volatile("s_waitcnt lgkmcnt(0)" ::: "memory");
        __builtin_amdgcn_s_barrier();
        if (t + 2 < NN / 64) STAGE(t + 2, cur);
    }
    // final tile (t = 31, buf 1): nothing left in flight to preserve
    asm volatile("s_waitcnt vmcnt(0)" ::: "memory");
    __builtin_amdgcn_s_barrier();
    COMPUTE(1);

#undef STAGE
#undef COMPUTE

    const float* disb = dis + (size_t)b * NN;
#pragma unroll
    for (int i = 0; i < 4; i++) {
#pragma unroll
        for (int r = 0; r < 4; r++) {
            const int nrow = n0 + i * 16 + quad * 4 + r;
            const float dn = disb[nrow];
#pragma unroll
            for (int j = 0; j < 2; j++) {
                const int ocol = ctile * 128 + w * 32 + j * 16 + l16;
                out[((size_t)b * NN + nrow) * DOUT + ocol] = dn * acc[i][j][r];
            }
        }
    }
}

extern "C" void kernel_launch(void* const* d_in, const int* in_sizes, int n_in,
                              void* d_out, int out_size, void* d_ws, size_t ws_size,
                              hipStream_t stream) {
    const float* x    = (const float*)d_in[0];
    const float* adj  = (const float*)d_in[1];
    const float* W    = (const float*)d_in[2];
    const float* bias = (const float*)d_in[3];
    float* out = (float*)d_out;

    float* dis = (float*)d_ws;                                             // 64 KB
    unsigned short* hT  = (unsigned short*)((char*)d_ws + 65536);          // 256*16416*2 = 8.4 MB
    unsigned short* abf = (unsigned short*)((char*)d_ws + 65536 + (size_t)DOUT * HP * 2); // 68 MB

    k_degree_cvt<<<RTOT, 256, 0, stream>>>(adj, dis, abf);
    k_proj<<<dim3(128, 2), 256, 0, stream>>>(x, W, bias, dis, hT);
    k_main<<<512, 256, 0, stream>>>(abf, hT, dis, out);
}

// Round 3
// 254.038 us; speedup vs baseline: 1.0575x; 1.0238x over previous
//
#include <hip/hip_runtime.h>
#include <hip/hip_bf16.h>

// GCN layer: out[b,n,o] = dis[b,n] * sum_m adj[b,n,m] * dis[b,m] * (x[b,m,:]@W[o,:] + bias[o])
//
// R10: drop the abf (bf16 adj) intermediate entirely. R9 lesson: K3's barrier
// structure is at its ceiling (counted-vmcnt = null; compiler/2nd-block already
// cover the drain). Remaining lever is TRAFFIC: abf was 68MB written by K1,
// read once by K3 (L3-hit), then dead -> its HBM write-back (~11us) is burned
// in the timed poison fills. Now K1 computes degrees only (no stores); K3
// stages A straight from adj f32 (L3-resident after K1's read): 8x float4 ->
// f2bf (bit-identical RNE to old abf) -> packed ds_write, in R7's proven
// BK=128 barrier-amortized structure. B-staging keeps gl_lds16 on bf16 hT.
// K1's summation order unchanged -> dis bits unchanged -> absmax unchanged.

#define BATCH 8
#define NN    2048
#define DIN   256
#define DOUT  256
#define RTOT  (BATCH * NN)   // 16384
#define HP    (RTOT + 32)    // 16416 padded hT row stride (elems)

typedef short  bf16x8  __attribute__((ext_vector_type(8)));
typedef short  short4v __attribute__((ext_vector_type(4)));
typedef float  f32x4   __attribute__((ext_vector_type(4)));

__device__ __forceinline__ short f2bf(float f) {
    union { float f; unsigned u; } v; v.f = f;
    unsigned r = v.u + 0x7fffu + ((v.u >> 16) & 1u);   // RNE
    return (short)(r >> 16);
}

__device__ __forceinline__ void gl_lds16(const unsigned short* g, unsigned short* l) {
    __builtin_amdgcn_global_load_lds(
        (const __attribute__((address_space(1))) unsigned int*)g,
        (__attribute__((address_space(3))) unsigned int*)l, 16, 0, 0);
}

// ---------------- K1: degrees -> dis only (summation order identical to R7) ----------------
__global__ __launch_bounds__(256) void k_degree(const float* __restrict__ adj,
                                                float* __restrict__ dis) {
    const int row = blockIdx.x;                 // 0..16383
    const int n = row & (NN - 1);
    const int tid = threadIdx.x;
    const float4* rp4 = (const float4*)(adj + (size_t)row * NN);

    float s = 0.f;
#pragma unroll
    for (int i = 0; i < 2; i++) {
        float4 v = rp4[tid + i * 256];
        s += (v.x + v.y) + (v.z + v.w);
    }
#pragma unroll
    for (int off = 32; off; off >>= 1) s += __shfl_down(s, off);
    __shared__ float red[4];
    if ((tid & 63) == 0) red[tid >> 6] = s;
    __syncthreads();
    if (tid == 0) {
        float tot  = (red[0] + red[1]) + (red[2] + red[3]);
        float diag = ((const float*)rp4)[n];
        dis[row]   = rsqrtf(tot - diag);
    }
}

// ---------------- K2: projection, transposed + dis-folded, padded hT ----------------
__global__ __launch_bounds__(256) void k_proj(const float* __restrict__ x,
                                              const float* __restrict__ W,
                                              const float* __restrict__ bias,
                                              const float* __restrict__ dis,
                                              unsigned short* __restrict__ hT) {
    const int mt  = blockIdx.y;           // 0..1   (o-tile of 128)
    const int nt  = blockIdx.x;           // 0..127 (r-tile of 128)
    const int tid = threadIdx.x;
    const int w = tid >> 6, lane = tid & 63;
    const int wr = w >> 1, wc = w & 1;
    const int l16 = lane & 15, quad = lane >> 4;

    __shared__ short As[128][32];
    __shared__ short Bs[128][32];

    f32x4 acc[4][4];
#pragma unroll
    for (int i = 0; i < 4; i++)
#pragma unroll
        for (int j = 0; j < 4; j++) acc[i][j] = (f32x4){0.f, 0.f, 0.f, 0.f};

    const float4* Wf4 = (const float4*)(W + (size_t)mt * 128 * DIN);
    const float4* Xf4 = (const float4*)(x + (size_t)nt * 128 * DIN);

    for (int kk = 0; kk < DIN / 32; kk++) {
        const int k0 = kk * 32;
        __syncthreads();
#pragma unroll
        for (int it = 0; it < 4; it++) {
            int idx = tid + it * 256;
            int r = idx >> 3, c = idx & 7;
            float4 va = Wf4[(size_t)r * (DIN / 4) + (k0 >> 2) + c];
            float4 vb = Xf4[(size_t)r * (DIN / 4) + (k0 >> 2) + c];
            short4v sa = { f2bf(va.x), f2bf(va.y), f2bf(va.z), f2bf(va.w) };
            short4v sb = { f2bf(vb.x), f2bf(vb.y), f2bf(vb.z), f2bf(vb.w) };
            *(short4v*)&As[r][c * 4] = sa;
            *(short4v*)&Bs[r][c * 4] = sb;
        }
        __syncthreads();
        bf16x8 af[4], bfv[4];
#pragma unroll
        for (int i = 0; i < 4; i++) af[i]  = *(bf16x8*)&As[wr * 64 + i * 16 + l16][quad * 8];
#pragma unroll
        for (int j = 0; j < 4; j++) bfv[j] = *(bf16x8*)&Bs[wc * 64 + j * 16 + l16][quad * 8];
#pragma unroll
        for (int i = 0; i < 4; i++)
#pragma unroll
            for (int j = 0; j < 4; j++)
                acc[i][j] = __builtin_amdgcn_mfma_f32_16x16x32_bf16(af[i], bfv[j], acc[i][j], 0, 0, 0);
    }

#pragma unroll
    for (int i = 0; i < 4; i++) {
        const int orow_base = mt * 128 + wr * 64 + i * 16 + quad * 4;
#pragma unroll
        for (int r = 0; r < 4; r++) {
            const int orow = orow_base + r;
            const float bb = bias[orow];
#pragma unroll
            for (int j = 0; j < 4; j++) {
                const int col = nt * 128 + wc * 64 + j * 16 + l16;
                float v = (acc[i][j][r] + bb) * dis[col];
                hT[(size_t)orow * HP + col] = (unsigned short)f2bf(v);
            }
        }
    }
}

// ---------------- K3: out = dis[n] * (bf16(adj) @ hT), BK=128 single-buffer ----------------
// Per batch: M=2048(n), K=2048(m), N=256(o). Block tile 64x128; 16 groups of BK=128
// (4 sub-windows of 32). Grid 512 = 2 blocks/CU: bx&7=batch (XCD L2 affinity),
// (bx>>3)&31=mtile, bx>>8=ctile (ctile pair on same XCD dedups adj reads in L2).
// A staged from adj f32 (L3-hot after K1): 8 float4 loads -> f2bf -> 4x 16B
// ds_write per group. B staged via gl_lds16 from bf16 hT. One drain per group.
__global__ __launch_bounds__(256, 2) void k_main(const float* __restrict__ adj,
                                                 const unsigned short* __restrict__ hT,
                                                 const float* __restrict__ dis,
                                                 float* __restrict__ out) {
    const int bx    = blockIdx.x;
    const int b     = bx & 7;
    const int mtile = (bx >> 3) & 31;
    const int ctile = bx >> 8;            // 0..1
    const int n0    = mtile * 64;
    const int tid  = threadIdx.x;
    const int w    = tid >> 6, lane = tid & 63;
    const int l16  = lane & 15, quad = lane >> 4;
    const int lr   = lane >> 2;           // 0..15 (staging row-within-group)
    const int lc   = (lane & 3) * 8;      // 0,8,16,24 (staging elem offset)

    __shared__ short As[4][64][32];       // 16 KB: 4 sub-windows of adj rows(n) x 32k
    __shared__ short Bs[4][128][32];      // 32 KB: 4 sub-windows of hT rows(o) x 32k

    // A source: adj row (b*NN + n0 + w*16 + lr), elem offset lc; as float4*
    const float4* agf4 = (const float4*)(adj + (size_t)(b * NN + n0 + w * 16 + lr) * NN + lc);
    const unsigned short* bgp0 = hT + (size_t)(ctile * 128 + w * 32 + lr) * HP + b * NN + lc;
    const unsigned short* bgp1 = bgp0 + (size_t)16 * HP;

    f32x4 acc[4][2];
#pragma unroll
    for (int i = 0; i < 4; i++)
#pragma unroll
        for (int j = 0; j < 2; j++) acc[i][j] = (f32x4){0.f, 0.f, 0.f, 0.f};

    for (int g = 0; g < NN / 128; g++) {          // 16 groups
        // B: 8 async gl_lds16 per thread (issue first, fly during A path)
#pragma unroll
        for (int s = 0; s < 4; s++) {
            const int ko = g * 128 + s * 32;
            gl_lds16(bgp0 + ko, (unsigned short*)&Bs[s][w * 32][0]);
            gl_lds16(bgp1 + ko, (unsigned short*)&Bs[s][w * 32 + 16][0]);
        }
        // A: 8 float4 f32 loads (L3-hot), convert RNE, 4x packed 16B ds_write
        float4 av0[4], av1[4];
#pragma unroll
        for (int s = 0; s < 4; s++) {
            av0[s] = agf4[g * 32 + s * 8];
            av1[s] = agf4[g * 32 + s * 8 + 1];
        }
#pragma unroll
        for (int s = 0; s < 4; s++) {
            bf16x8 pk = { f2bf(av0[s].x), f2bf(av0[s].y), f2bf(av0[s].z), f2bf(av0[s].w),
                          f2bf(av1[s].x), f2bf(av1[s].y), f2bf(av1[s].z), f2bf(av1[s].w) };
            *(bf16x8*)&As[s][w * 16 + lr][lc] = pk;
        }
        __syncthreads();   // drain staging once per 128-K of work
        // Consume: 32 MFMA + 24 ds_read_b128 per wave.
#pragma unroll
        for (int s = 0; s < 4; s++) {
            bf16x8 af[4], bfv[2];
#pragma unroll
            for (int i = 0; i < 4; i++) af[i]  = *(bf16x8*)&As[s][i * 16 + l16][quad * 8];
#pragma unroll
            for (int j = 0; j < 2; j++) bfv[j] = *(bf16x8*)&Bs[s][w * 32 + j * 16 + l16][quad * 8];
#pragma unroll
            for (int i = 0; i < 4; i++)
#pragma unroll
                for (int j = 0; j < 2; j++)
                    acc[i][j] = __builtin_amdgcn_mfma_f32_16x16x32_bf16(af[i], bfv[j], acc[i][j], 0, 0, 0);
        }
        __syncthreads();   // all ds_reads retired before restage
    }

    const float* disb = dis + (size_t)b * NN;
#pragma unroll
    for (int i = 0; i < 4; i++) {
#pragma unroll
        for (int r = 0; r < 4; r++) {
            const int nrow = n0 + i * 16 + quad * 4 + r;
            const float dn = disb[nrow];
#pragma unroll
            for (int j = 0; j < 2; j++) {
                const int ocol = ctile * 128 + w * 32 + j * 16 + l16;
                out[((size_t)b * NN + nrow) * DOUT + ocol] = dn * acc[i][j][r];
            }
        }
    }
}

extern "C" void kernel_launch(void* const* d_in, const int* in_sizes, int n_in,
                              void* d_out, int out_size, void* d_ws, size_t ws_size,
                              hipStream_t stream) {
    const float* x    = (const float*)d_in[0];
    const float* adj  = (const float*)d_in[1];
    const float* W    = (const float*)d_in[2];
    const float* bias = (const float*)d_in[3];
    float* out = (float*)d_out;

    float* dis = (float*)d_ws;                                             // 64 KB
    unsigned short* hT  = (unsigned short*)((char*)d_ws + 65536);          // 256*16416*2 = 8.4 MB

    k_degree<<<RTOT, 256, 0, stream>>>(adj, dis);
    k_proj<<<dim3(128, 2), 256, 0, stream>>>(x, W, bias, dis, hT);
    k_main<<<512, 256, 0, stream>>>(adj, hT, dis, out);
}

// Round 4
// 244.143 us; speedup vs baseline: 1.1004x; 1.0405x over previous
//
#include <hip/hip_runtime.h>
#include <hip/hip_bf16.h>

// GCN layer: out[b,n,o] = dis[b,n] * sum_m adj[b,n,m] * dis[b,m] * (x[b,m,:]@W[o,:] + bias[o])
//
// R11: fuse K1(degree)+K2(proj) into one kernel; K2 part no longer folds dis
// (moved to K3's A-staging as an f32 multiply before RNE->bf16), so the two
// parts are independent: proj blocks (0..255) dispatch first and their
// MFMA/latency work hides under the 16384 degree blocks' BW-bound adj read.
// K3: A = bf16(adj[n,m] * dis[b,m]) staged from f32 adj (L3-hot) with dis
// slice L1-hot (8KB/batch, lane-broadcast); epilogue d_n scale unchanged.
// R10 confirmed the traffic model (-6us from dropping abf write-back).

#define BATCH 8
#define NN    2048
#define DIN   256
#define DOUT  256
#define RTOT  (BATCH * NN)   // 16384
#define HP    (RTOT + 32)    // 16416 padded hT row stride (elems)

typedef short  bf16x8  __attribute__((ext_vector_type(8)));
typedef short  short4v __attribute__((ext_vector_type(4)));
typedef float  f32x4   __attribute__((ext_vector_type(4)));

__device__ __forceinline__ short f2bf(float f) {
    union { float f; unsigned u; } v; v.f = f;
    unsigned r = v.u + 0x7fffu + ((v.u >> 16) & 1u);   // RNE
    return (short)(r >> 16);
}

__device__ __forceinline__ void gl_lds16(const unsigned short* g, unsigned short* l) {
    __builtin_amdgcn_global_load_lds(
        (const __attribute__((address_space(1))) unsigned int*)g,
        (__attribute__((address_space(3))) unsigned int*)l, 16, 0, 0);
}

// ---------------- K12: blocks 0..255 = projection (no dis), 256.. = degrees ----------------
__global__ __launch_bounds__(256) void k_deg_proj(const float* __restrict__ adj,
                                                  const float* __restrict__ x,
                                                  const float* __restrict__ W,
                                                  const float* __restrict__ bias,
                                                  float* __restrict__ dis,
                                                  unsigned short* __restrict__ hT) {
    const int tid = threadIdx.x;

    if (blockIdx.x < 256) {
        // ---- projection part: hT[o, r] = bf16((x@W^T)[r,o] + b[o]), padded rows ----
        const int bid = blockIdx.x;
        const int mt  = bid >> 7;         // 0..1   (o-tile of 128)
        const int nt  = bid & 127;        // 0..127 (r-tile of 128)
        const int w = tid >> 6, lane = tid & 63;
        const int wr = w >> 1, wc = w & 1;
        const int l16 = lane & 15, quad = lane >> 4;

        __shared__ short As[128][32];
        __shared__ short Bs[128][32];

        f32x4 acc[4][4];
#pragma unroll
        for (int i = 0; i < 4; i++)
#pragma unroll
            for (int j = 0; j < 4; j++) acc[i][j] = (f32x4){0.f, 0.f, 0.f, 0.f};

        const float4* Wf4 = (const float4*)(W + (size_t)mt * 128 * DIN);
        const float4* Xf4 = (const float4*)(x + (size_t)nt * 128 * DIN);

        for (int kk = 0; kk < DIN / 32; kk++) {
            const int k0 = kk * 32;
            __syncthreads();
#pragma unroll
            for (int it = 0; it < 4; it++) {
                int idx = tid + it * 256;
                int r = idx >> 3, c = idx & 7;
                float4 va = Wf4[(size_t)r * (DIN / 4) + (k0 >> 2) + c];
                float4 vb = Xf4[(size_t)r * (DIN / 4) + (k0 >> 2) + c];
                short4v sa = { f2bf(va.x), f2bf(va.y), f2bf(va.z), f2bf(va.w) };
                short4v sb = { f2bf(vb.x), f2bf(vb.y), f2bf(vb.z), f2bf(vb.w) };
                *(short4v*)&As[r][c * 4] = sa;
                *(short4v*)&Bs[r][c * 4] = sb;
            }
            __syncthreads();
            bf16x8 af[4], bfv[4];
#pragma unroll
            for (int i = 0; i < 4; i++) af[i]  = *(bf16x8*)&As[wr * 64 + i * 16 + l16][quad * 8];
#pragma unroll
            for (int j = 0; j < 4; j++) bfv[j] = *(bf16x8*)&Bs[wc * 64 + j * 16 + l16][quad * 8];
#pragma unroll
            for (int i = 0; i < 4; i++)
#pragma unroll
                for (int j = 0; j < 4; j++)
                    acc[i][j] = __builtin_amdgcn_mfma_f32_16x16x32_bf16(af[i], bfv[j], acc[i][j], 0, 0, 0);
        }

#pragma unroll
        for (int i = 0; i < 4; i++) {
            const int orow_base = mt * 128 + wr * 64 + i * 16 + quad * 4;
#pragma unroll
            for (int r = 0; r < 4; r++) {
                const int orow = orow_base + r;
                const float bb = bias[orow];
#pragma unroll
                for (int j = 0; j < 4; j++) {
                    const int col = nt * 128 + wc * 64 + j * 16 + l16;
                    float v = acc[i][j][r] + bb;               // dis NOT folded here anymore
                    hT[(size_t)orow * HP + col] = (unsigned short)f2bf(v);
                }
            }
        }
    } else {
        // ---- degree part: dis[row] = rsqrt(rowsum - diag); order identical to R10 ----
        const int row = blockIdx.x - 256;           // 0..16383
        const int n = row & (NN - 1);
        const float4* rp4 = (const float4*)(adj + (size_t)row * NN);

        float s = 0.f;
#pragma unroll
        for (int i = 0; i < 2; i++) {
            float4 v = rp4[tid + i * 256];
            s += (v.x + v.y) + (v.z + v.w);
        }
#pragma unroll
        for (int off = 32; off; off >>= 1) s += __shfl_down(s, off);
        __shared__ float red[4];
        if ((tid & 63) == 0) red[tid >> 6] = s;
        __syncthreads();
        if (tid == 0) {
            float tot  = (red[0] + red[1]) + (red[2] + red[3]);
            float diag = ((const float*)rp4)[n];
            dis[row]   = rsqrtf(tot - diag);
        }
    }
}

// ---------------- K3: out = dis[n] * ((adj .* dis_m) @ hT), BK=128 single-buffer ----------------
// Per batch: M=2048(n), K=2048(m), N=256(o). Block tile 64x128; 16 groups of BK=128
// (4 sub-windows of 32). Grid 512 = 2 blocks/CU: bx&7=batch (XCD L2 affinity),
// (bx>>3)&31=mtile, bx>>8=ctile. A staged from adj f32 (L3-hot) with dis[b,m]
// folded in f32 before RNE->bf16; dis slice is L1-hot (8KB/batch, lane-broadcast).
// B staged via gl_lds16 from bf16 hT (now dis-free). One drain per group.
__global__ __launch_bounds__(256, 2) void k_main(const float* __restrict__ adj,
                                                 const unsigned short* __restrict__ hT,
                                                 const float* __restrict__ dis,
                                                 float* __restrict__ out) {
    const int bx    = blockIdx.x;
    const int b     = bx & 7;
    const int mtile = (bx >> 3) & 31;
    const int ctile = bx >> 8;            // 0..1
    const int n0    = mtile * 64;
    const int tid  = threadIdx.x;
    const int w    = tid >> 6, lane = tid & 63;
    const int l16  = lane & 15, quad = lane >> 4;
    const int lr   = lane >> 2;           // 0..15 (staging row-within-group)
    const int lc   = (lane & 3) * 8;      // 0,8,16,24 (staging elem offset)

    __shared__ short As[4][64][32];       // 16 KB: 4 sub-windows of adj rows(n) x 32k
    __shared__ short Bs[4][128][32];      // 32 KB: 4 sub-windows of hT rows(o) x 32k

    const float* disb = dis + (size_t)b * NN;
    // A source: adj row (b*NN + n0 + w*16 + lr), elem offset lc; as float4*
    const float4* agf4 = (const float4*)(adj + (size_t)(b * NN + n0 + w * 16 + lr) * NN + lc);
    const unsigned short* bgp0 = hT + (size_t)(ctile * 128 + w * 32 + lr) * HP + b * NN + lc;
    const unsigned short* bgp1 = bgp0 + (size_t)16 * HP;

    f32x4 acc[4][2];
#pragma unroll
    for (int i = 0; i < 4; i++)
#pragma unroll
        for (int j = 0; j < 2; j++) acc[i][j] = (f32x4){0.f, 0.f, 0.f, 0.f};

    for (int g = 0; g < NN / 128; g++) {          // 16 groups
        // B: 8 async gl_lds16 per thread (issue first, fly during A path)
#pragma unroll
        for (int s = 0; s < 4; s++) {
            const int ko = g * 128 + s * 32;
            gl_lds16(bgp0 + ko, (unsigned short*)&Bs[s][w * 32][0]);
            gl_lds16(bgp1 + ko, (unsigned short*)&Bs[s][w * 32 + 16][0]);
        }
        // A: 8 float4 f32 loads (L3-hot) + dis fold (L1-hot) -> RNE -> 16B ds_write
        float4 av0[4], av1[4];
#pragma unroll
        for (int s = 0; s < 4; s++) {
            av0[s] = agf4[g * 32 + s * 8];
            av1[s] = agf4[g * 32 + s * 8 + 1];
        }
#pragma unroll
        for (int s = 0; s < 4; s++) {
            const float* dp = disb + g * 128 + s * 32 + lc;
            float4 dv0 = *(const float4*)dp;
            float4 dv1 = *(const float4*)(dp + 4);
            bf16x8 pk = { f2bf(av0[s].x * dv0.x), f2bf(av0[s].y * dv0.y),
                          f2bf(av0[s].z * dv0.z), f2bf(av0[s].w * dv0.w),
                          f2bf(av1[s].x * dv1.x), f2bf(av1[s].y * dv1.y),
                          f2bf(av1[s].z * dv1.z), f2bf(av1[s].w * dv1.w) };
            *(bf16x8*)&As[s][w * 16 + lr][lc] = pk;
        }
        __syncthreads();   // drain staging once per 128-K of work
        // Consume: 32 MFMA + 24 ds_read_b128 per wave.
#pragma unroll
        for (int s = 0; s < 4; s++) {
            bf16x8 af[4], bfv[2];
#pragma unroll
            for (int i = 0; i < 4; i++) af[i]  = *(bf16x8*)&As[s][i * 16 + l16][quad * 8];
#pragma unroll
            for (int j = 0; j < 2; j++) bfv[j] = *(bf16x8*)&Bs[s][w * 32 + j * 16 + l16][quad * 8];
#pragma unroll
            for (int i = 0; i < 4; i++)
#pragma unroll
                for (int j = 0; j < 2; j++)
                    acc[i][j] = __builtin_amdgcn_mfma_f32_16x16x32_bf16(af[i], bfv[j], acc[i][j], 0, 0, 0);
        }
        __syncthreads();   // all ds_reads retired before restage
    }

#pragma unroll
    for (int i = 0; i < 4; i++) {
#pragma unroll
        for (int r = 0; r < 4; r++) {
            const int nrow = n0 + i * 16 + quad * 4 + r;
            const float dn = disb[nrow];
#pragma unroll
            for (int j = 0; j < 2; j++) {
                const int ocol = ctile * 128 + w * 32 + j * 16 + l16;
                out[((size_t)b * NN + nrow) * DOUT + ocol] = dn * acc[i][j][r];
            }
        }
    }
}

extern "C" void kernel_launch(void* const* d_in, const int* in_sizes, int n_in,
                              void* d_out, int out_size, void* d_ws, size_t ws_size,
                              hipStream_t stream) {
    const float* x    = (const float*)d_in[0];
    const float* adj  = (const float*)d_in[1];
    const float* W    = (const float*)d_in[2];
    const float* bias = (const float*)d_in[3];
    float* out = (float*)d_out;

    float* dis = (float*)d_ws;                                             // 64 KB
    unsigned short* hT  = (unsigned short*)((char*)d_ws + 65536);          // 256*16416*2 = 8.4 MB

    k_deg_proj<<<256 + RTOT, 256, 0, stream>>>(adj, x, W, bias, dis, hT);
    k_main<<<512, 256, 0, stream>>>(adj, hT, dis, out);
}